// Round 9
// baseline (407.771 us; speedup 1.0000x reference)
//
#include <hip/hip_runtime.h>
#include <hip/hip_bf16.h>

#define NN 131072      // nodes
#define EE 2097152     // edges
#define NG 256         // graphs
#define TT 8
#define NB 512         // dst buckets (256 nodes each)
#define NBLK 1024      // partition blocks (2048 edges each)
#define SCAP 16        // per-(block,bucket) segment capacity
#define MAXW 32        // ELL width (overflow -> exact inline fix-up)
#define OVFA_CAP 4096
#define OVFB_CAP 16384

// ---------- zero (int) ----------
__global__ __launch_bounds__(256) void k_zero_i(int* __restrict__ p, int n) {
  int i = blockIdx.x * 256 + threadIdx.x;
  if (i < n) p[i] = 0;
}

// ---------- pass 1: block-private partition, LDS cursors, block-major layout ----------
__global__ __launch_bounds__(256) void k_part2(const int* __restrict__ ei, int* __restrict__ pairs,
                                               unsigned char* __restrict__ cnt2, int* __restrict__ ovfAcnt,
                                               int2* __restrict__ ovfA) {
  __shared__ int lcur[NB];
  int tid = threadIdx.x, blk = blockIdx.x;
  lcur[tid] = 0; lcur[tid + 256] = 0;
  __syncthreads();
  int e0 = blk * (EE / NBLK);
#pragma unroll
  for (int i = 0; i < (EE / NBLK) / 256; ++i) {
    int e = e0 + i * 256 + tid;
    int s = ei[e], d = ei[EE + e];
    int b = d >> 8;
    int k = atomicAdd(&lcur[b], 1);
    if (k < SCAP)
      pairs[((size_t)blk * NB + b) * SCAP + k] = ((d & 255) << 17) | s;
    else {
      int oi = atomicAdd(ovfAcnt, 1);
      if (oi < OVFA_CAP) ovfA[oi] = make_int2(d, s);
    }
  }
  __syncthreads();
  cnt2[(size_t)blk * NB + tid] = (unsigned char)min(lcur[tid], SCAP);
  cnt2[(size_t)blk * NB + tid + 256] = (unsigned char)min(lcur[tid + 256], SCAP);
}

// ---------- pass 2: per-bucket ELL build in LDS ----------
__global__ __launch_bounds__(256) void k_bucket(const int* __restrict__ pairs, const unsigned char* __restrict__ cnt2,
                                                int* __restrict__ col, int* __restrict__ cnt,
                                                const int* __restrict__ ovfAcnt, const int2* __restrict__ ovfA,
                                                int* __restrict__ ovfBcnt, int2* __restrict__ ovfB) {
  __shared__ int lcnt[256];
  __shared__ int lell[256 * MAXW];
  __shared__ unsigned char scnt[NBLK];
  int b = blockIdx.x, tid = threadIdx.x;
  lcnt[tid] = 0;
#pragma unroll
  for (int i = 0; i < NBLK / 256; ++i)
    scnt[tid + i * 256] = cnt2[(size_t)(tid + i * 256) * NB + b];
  __syncthreads();
  for (int idx = tid; idx < NBLK * SCAP; idx += 256) {
    int blk = idx >> 4, slot = idx & (SCAP - 1);
    if (slot < (int)scnt[blk]) {
      int p = pairs[(size_t)blk * (NB * SCAP) + b * SCAP + slot];
      int s = p & 0x1FFFF, dl = p >> 17;
      int k = atomicAdd(&lcnt[dl], 1);
      if (k < MAXW) lell[dl * MAXW + k] = s;
      else {
        int oi = atomicAdd(ovfBcnt, 1);
        if (oi < OVFB_CAP) ovfB[oi] = make_int2(b * 256 + dl, s);
      }
    }
  }
  int na = min(*ovfAcnt, OVFA_CAP);
  for (int i = tid; i < na; i += 256) {
    int d = ovfA[i].x, s = ovfA[i].y;
    if ((d >> 8) == b) {
      int dl = d & 255;
      int k = atomicAdd(&lcnt[dl], 1);
      if (k < MAXW) lell[dl * MAXW + k] = s;
      else {
        int oi = atomicAdd(ovfBcnt, 1);
        if (oi < OVFB_CAP) ovfB[oi] = make_int2(d, s);
      }
    }
  }
  __syncthreads();
  int4* dst4 = (int4*)(col + (size_t)b * 256 * MAXW);
  const int4* src4 = (const int4*)lell;
#pragma unroll
  for (int i = 0; i < (256 * MAXW / 4) / 256; ++i)
    dst4[tid + i * 256] = src4[tid + i * 256];
  cnt[b * 256 + tid] = lcnt[tid];
}

// ---------- GEMM (layer 1): Y = X @ W ----------
__global__ __launch_bounds__(256) void k_gemm(const float* __restrict__ X, const float* __restrict__ W,
                                              float* __restrict__ Y) {
  __shared__ float xs[64 * 64];
  __shared__ float ws[64 * 64];
  int tid = threadIdx.x;
  size_t row0 = (size_t)blockIdx.x * 64;
#pragma unroll
  for (int i = 0; i < 16; ++i) ws[tid + i * 256] = W[tid + i * 256];
#pragma unroll
  for (int i = 0; i < 4; ++i) {
    int idx = tid + i * 256;
    int r = idx >> 4, q = idx & 15;
    float4 v = ((const float4*)(X + (row0 + r) * 64))[q];
    *(float4*)&xs[idx * 4] = v;
  }
  __syncthreads();
  int c = tid & 63, rg = tid >> 6;
  float acc[16];
#pragma unroll
  for (int i = 0; i < 16; ++i) acc[i] = 0.f;
#pragma unroll 4
  for (int kq = 0; kq < 16; ++kq) {
    float w0 = ws[(kq * 4 + 0) * 64 + c];
    float w1 = ws[(kq * 4 + 1) * 64 + c];
    float w2 = ws[(kq * 4 + 2) * 64 + c];
    float w3 = ws[(kq * 4 + 3) * 64 + c];
#pragma unroll
    for (int i = 0; i < 16; ++i) {
      const float4 xv = *(const float4*)&xs[(rg + i * 4) * 64 + kq * 4];
      acc[i] += xv.x * w0 + xv.y * w1 + xv.z * w2 + xv.w * w3;
    }
  }
#pragma unroll
  for (int i = 0; i < 16; ++i)
    Y[(row0 + rg + (size_t)i * 4) * 64 + c] = acc[i];
}

// ---------- ELL gather, 2 nodes/wave, optional inline bias+relu on H rows, inline ovf ----------
template <int RELU>
__global__ __launch_bounds__(256) void k_gather(const float* __restrict__ H, const int* __restrict__ cnt,
                                                const int* __restrict__ col,
                                                const int* __restrict__ ovfcnt, const int2* __restrict__ ovf,
                                                const float* __restrict__ bias, float* __restrict__ agg) {
  int lane = threadIdx.x & 63;
  int n0 = (blockIdx.x * 4 + (threadIdx.x >> 6)) * 2;
  int n1 = n0 + 1;
  float b = RELU ? bias[lane] : 0.f;
  auto ld = [&](int s) -> float {
    float v = H[(size_t)s * 64 + lane];
    return RELU ? fmaxf(v + b, 0.f) : v;
  };
  int deg0 = cnt[n0], deg1 = cnt[n1];
  float dn0 = rsqrtf((float)deg0 + 1.0f), dn1 = rsqrtf((float)deg1 + 1.0f);
  float acc0 = ld(n0) * (dn0 * dn0);
  float acc1 = ld(n1) * (dn1 * dn1);
  int m0 = min(deg0, MAXW), m1 = min(deg1, MAXW);
  const int* c0r = col + (size_t)n0 * MAXW;
  const int* c1r = col + (size_t)n1 * MAXW;
  int myc0 = (lane < m0) ? c0r[lane] : 0;
  int myc1 = (lane < m1) ? c1r[lane] : 0;
  float md0 = (lane < m0) ? rsqrtf((float)cnt[myc0] + 1.0f) : 0.f;
  float md1 = (lane < m1) ? rsqrtf((float)cnt[myc1] + 1.0f) : 0.f;
  int mm = max(m0, m1);
  for (int j = 0; j < mm; j += 4) {
    float h[8], cc[8];
#pragma unroll
    for (int k = 0; k < 4; ++k) {
      if (j + k < m0) {          // wave-uniform branch
        int s = __shfl(myc0, j + k);
        cc[k] = __shfl(md0, j + k);
        h[k] = ld(s);
      } else { h[k] = 0.f; cc[k] = 0.f; }
      if (j + k < m1) {
        int s = __shfl(myc1, j + k);
        cc[4 + k] = __shfl(md1, j + k);
        h[4 + k] = ld(s);
      } else { h[4 + k] = 0.f; cc[4 + k] = 0.f; }
    }
#pragma unroll
    for (int k = 0; k < 4; ++k) {
      acc0 += h[k] * (cc[k] * dn0);
      acc1 += h[4 + k] * (cc[4 + k] * dn1);
    }
  }
  // inline exact ELL-overflow fix-up (na is almost always 0)
  int na = min(*ovfcnt, OVFB_CAP);
  for (int i = 0; i < na; ++i) {
    int2 e = ovf[i];
    if (e.x == n0) acc0 += ld(e.y) * (rsqrtf((float)cnt[e.y] + 1.0f) * dn0);
    else if (e.x == n1) acc1 += ld(e.y) * (rsqrtf((float)cnt[e.y] + 1.0f) * dn1);
  }
  agg[(size_t)n0 * 64 + lane] = acc0;
  agg[(size_t)n1 * 64 + lane] = acc1;
}

// ---------- node blur (pre-W2): zpre[g,t,f] = sum_rr w[rr]*G2[g,rr,t,f] ----------
__global__ __launch_bounds__(256) void k_blur(const float* __restrict__ G2, float* __restrict__ zpre) {
  int idx = blockIdx.x * 256 + threadIdx.x;
  if (idx >= NG * TT * 64) return;
  int f = idx & 63, t = (idx >> 6) & 7, g = idx >> 9;
  const float* base = G2 + ((size_t)g * 512 + (size_t)t) * 64 + f;
  float acc = 0.f;
#pragma unroll
  for (int rr = 0; rr < 64; ++rr) {
    float w = (float)(63 - rr) * (1.0f / 63.0f);
    acc += w * base[(size_t)rr * 8 * 64];
  }
  zpre[idx] = acc;
}

// ---------- classifier head: z = zpre@W2 + 32*b2, then lin1->LIF->lin2->LIF->lin3 ----------
__global__ __launch_bounds__(64) void k_head(const float* __restrict__ zpre,
    const float* __restrict__ cw, const float* __restrict__ cb,
    const float* __restrict__ l1w, const float* __restrict__ l1b,
    const float* __restrict__ l2w, const float* __restrict__ l2b,
    const float* __restrict__ l3w, const float* __restrict__ l3b,
    float* __restrict__ out) {
  __shared__ float zp[512];
  __shared__ float zs[512];
  __shared__ float r[64];
  int g = blockIdx.x, c = threadIdx.x;
#pragma unroll
  for (int i = 0; i < 8; ++i) zp[c + i * 64] = zpre[(size_t)g * 512 + c + i * 64];
  __syncthreads();
  // z[t,c] = 32*cb[c] + sum_k zp[t,k]*cw[k,c]
  float zt[8];
  float cbv = 32.0f * cb[c];
#pragma unroll
  for (int t = 0; t < 8; ++t) zt[t] = cbv;
  for (int k = 0; k < 64; ++k) {
    float w = cw[k * 64 + c];
#pragma unroll
    for (int t = 0; t < 8; ++t) zt[t] += zp[t * 64 + k] * w;
  }
#pragma unroll
  for (int t = 0; t < 8; ++t) zs[t * 64 + c] = zt[t];
  __syncthreads();
  float a = l1b[c];
  for (int j = 0; j < 512; ++j) a += zs[j] * l1w[j * 64 + c];
  float mem = 0.f, rate = 0.f;
#pragma unroll
  for (int s = 0; s < 4; ++s) {
    float reset = (mem > 1.0f) ? 1.0f : 0.0f;
    mem = 0.9f * mem + a - reset;
    if (mem - 1.0f > 0.0f) rate += 1.0f;
  }
  r[c] = rate * 0.25f;
  __syncthreads();
  float a2 = l2b[c];
#pragma unroll
  for (int j = 0; j < 64; ++j) a2 += r[j] * l2w[j * 64 + c];
  __syncthreads();
  mem = 0.f; rate = 0.f;
#pragma unroll
  for (int s = 0; s < 4; ++s) {
    float reset = (mem > 1.0f) ? 1.0f : 0.0f;
    mem = 0.9f * mem + a2 - reset;
    if (mem - 1.0f > 0.0f) rate += 1.0f;
  }
  r[c] = rate * 0.25f;
  __syncthreads();
  if (c < 10) {
    float o = l3b[c];
#pragma unroll
    for (int j = 0; j < 64; ++j) o += r[j] * l3w[j * 10 + c];
    out[(size_t)g * 10 + c] = o;
  }
}

extern "C" void kernel_launch(void* const* d_in, const int* in_sizes, int n_in,
                              void* d_out, int out_size, void* d_ws, size_t ws_size,
                              hipStream_t stream) {
  const float* x   = (const float*)d_in[0];
  const int*   ei  = (const int*)d_in[1];
  const float* c1w = (const float*)d_in[3];
  const float* c1b = (const float*)d_in[4];
  const float* c2w = (const float*)d_in[5];
  const float* c2b = (const float*)d_in[6];
  const float* l1w = (const float*)d_in[7];
  const float* l1b = (const float*)d_in[8];
  const float* l2w = (const float*)d_in[9];
  const float* l2b = (const float*)d_in[10];
  const float* l3w = (const float*)d_in[11];
  const float* l3b = (const float*)d_in[12];
  float* out = (float*)d_out;

  char* w = (char*)d_ws;
  size_t off = 0;
  float* bufA = (float*)(w + off); off += (size_t)NN * 64 * 4;       // 33.5 MB (pairs overlay)
  float* bufB = (float*)(w + off); off += (size_t)NN * 64 * 4;       // 33.5 MB
  int* col    = (int*)(w + off);   off += (size_t)NN * MAXW * 4;     // 16.8 MB
  int* cnt    = (int*)(w + off);   off += (size_t)NN * 4;
  unsigned char* cnt2 = (unsigned char*)(w + off); off += (size_t)NBLK * NB; // 0.5 MB
  float* zpre = (float*)(w + off); off += (size_t)NG * TT * 64 * 4;  // 0.5 MB
  int* meta   = (int*)(w + off);   off += 16 * 4;
  int2* ovfA  = (int2*)(w + off);  off += (size_t)OVFA_CAP * 8;
  int2* ovfB  = (int2*)(w + off);  off += (size_t)OVFB_CAP * 8;
  int* ovfAcnt = meta;
  int* ovfBcnt = meta + 1;
  int* pairs   = (int*)bufA;       // 1024*512*16*4 = 33.5 MB, dead before GEMM1

  // graph build
  k_zero_i<<<1, 256, 0, stream>>>(meta, 16);
  k_part2<<<NBLK, 256, 0, stream>>>(ei, pairs, cnt2, ovfAcnt, ovfA);
  k_bucket<<<NB, 256, 0, stream>>>(pairs, cnt2, col, cnt, ovfAcnt, ovfA, ovfBcnt, ovfB);

  // layer 1: H1 = x @ W1 (bufA); agg1 = S*H1 (bufB)
  k_gemm<<<NN / 64, 256, 0, stream>>>(x, c1w, bufA);
  k_gather<0><<<NN / 8, 256, 0, stream>>>(bufA, cnt, col, ovfBcnt, ovfB, nullptr, bufB);

  // layer 2 (W2 deferred past blur): G2 = S*relu(agg1 + b1) (bufA)
  k_gather<1><<<NN / 8, 256, 0, stream>>>(bufB, cnt, col, ovfBcnt, ovfB, c1b, bufA);

  // blur (pre-W2) + head (applies W2 + 32*b2, then MLP/LIF)
  k_blur<<<NG * TT * 64 / 256, 256, 0, stream>>>(bufA, zpre);
  k_head<<<NG, 64, 0, stream>>>(zpre, c2w, c2b, l1w, l1b, l2w, l2b, l3w, l3b, out);
}

// Round 10
// 351.367 us; speedup vs baseline: 1.1605x; 1.1605x over previous
//
#include <hip/hip_runtime.h>
#include <hip/hip_bf16.h>

#define NN 131072      // nodes
#define EE 2097152     // edges
#define NG 256         // graphs
#define TT 8
#define NB 512         // dst buckets (256 nodes each)
#define NBLK 1024      // partition blocks (2048 edges each)
#define SCAP 16        // per-(block,bucket) segment capacity
#define MAXW 32        // ELL width (overflow -> exact k_ovf fix-up)
#define OVFA_CAP 4096
#define OVFB_CAP 16384

// ---------- zero (int) ----------
__global__ __launch_bounds__(256) void k_zero_i(int* __restrict__ p, int n) {
  int i = blockIdx.x * 256 + threadIdx.x;
  if (i < n) p[i] = 0;
}

// ---------- pass 1: block-private partition, LDS cursors, block-major layout ----------
__global__ __launch_bounds__(256) void k_part2(const int* __restrict__ ei, int* __restrict__ pairs,
                                               unsigned char* __restrict__ cnt2, int* __restrict__ ovfAcnt,
                                               int2* __restrict__ ovfA) {
  __shared__ int lcur[NB];
  int tid = threadIdx.x, blk = blockIdx.x;
  lcur[tid] = 0; lcur[tid + 256] = 0;
  __syncthreads();
  int e0 = blk * (EE / NBLK);
#pragma unroll
  for (int i = 0; i < (EE / NBLK) / 256; ++i) {
    int e = e0 + i * 256 + tid;
    int s = ei[e], d = ei[EE + e];
    int b = d >> 8;
    int k = atomicAdd(&lcur[b], 1);
    if (k < SCAP)
      pairs[((size_t)blk * NB + b) * SCAP + k] = ((d & 255) << 17) | s;
    else {
      int oi = atomicAdd(ovfAcnt, 1);
      if (oi < OVFA_CAP) ovfA[oi] = make_int2(d, s);
    }
  }
  __syncthreads();
  cnt2[(size_t)blk * NB + tid] = (unsigned char)min(lcur[tid], SCAP);
  cnt2[(size_t)blk * NB + tid + 256] = (unsigned char)min(lcur[tid + 256], SCAP);
}

// ---------- pass 2: per-bucket ELL build in LDS ----------
__global__ __launch_bounds__(256) void k_bucket(const int* __restrict__ pairs, const unsigned char* __restrict__ cnt2,
                                                int* __restrict__ col, int* __restrict__ cnt,
                                                const int* __restrict__ ovfAcnt, const int2* __restrict__ ovfA,
                                                int* __restrict__ ovfBcnt, int2* __restrict__ ovfB) {
  __shared__ int lcnt[256];
  __shared__ int lell[256 * MAXW];
  __shared__ unsigned char scnt[NBLK];
  int b = blockIdx.x, tid = threadIdx.x;
  lcnt[tid] = 0;
#pragma unroll
  for (int i = 0; i < NBLK / 256; ++i)
    scnt[tid + i * 256] = cnt2[(size_t)(tid + i * 256) * NB + b];
  __syncthreads();
  for (int idx = tid; idx < NBLK * SCAP; idx += 256) {
    int blk = idx >> 4, slot = idx & (SCAP - 1);
    if (slot < (int)scnt[blk]) {
      int p = pairs[(size_t)blk * (NB * SCAP) + b * SCAP + slot];
      int s = p & 0x1FFFF, dl = p >> 17;
      int k = atomicAdd(&lcnt[dl], 1);
      if (k < MAXW) lell[dl * MAXW + k] = s;
      else {
        int oi = atomicAdd(ovfBcnt, 1);
        if (oi < OVFB_CAP) ovfB[oi] = make_int2(b * 256 + dl, s);
      }
    }
  }
  int na = min(*ovfAcnt, OVFA_CAP);
  for (int i = tid; i < na; i += 256) {
    int d = ovfA[i].x, s = ovfA[i].y;
    if ((d >> 8) == b) {
      int dl = d & 255;
      int k = atomicAdd(&lcnt[dl], 1);
      if (k < MAXW) lell[dl * MAXW + k] = s;
      else {
        int oi = atomicAdd(ovfBcnt, 1);
        if (oi < OVFB_CAP) ovfB[oi] = make_int2(d, s);
      }
    }
  }
  __syncthreads();
  int4* dst4 = (int4*)(col + (size_t)b * 256 * MAXW);
  const int4* src4 = (const int4*)lell;
#pragma unroll
  for (int i = 0; i < (256 * MAXW / 4) / 256; ++i)
    dst4[tid + i * 256] = src4[tid + i * 256];
  cnt[b * 256 + tid] = lcnt[tid];
}

// ---------- GEMM (layer 1): Y = X @ W ----------
__global__ __launch_bounds__(256) void k_gemm(const float* __restrict__ X, const float* __restrict__ W,
                                              float* __restrict__ Y) {
  __shared__ float xs[64 * 64];
  __shared__ float ws[64 * 64];
  int tid = threadIdx.x;
  size_t row0 = (size_t)blockIdx.x * 64;
#pragma unroll
  for (int i = 0; i < 16; ++i) ws[tid + i * 256] = W[tid + i * 256];
#pragma unroll
  for (int i = 0; i < 4; ++i) {
    int idx = tid + i * 256;
    int r = idx >> 4, q = idx & 15;
    float4 v = ((const float4*)(X + (row0 + r) * 64))[q];
    *(float4*)&xs[idx * 4] = v;
  }
  __syncthreads();
  int c = tid & 63, rg = tid >> 6;
  float acc[16];
#pragma unroll
  for (int i = 0; i < 16; ++i) acc[i] = 0.f;
#pragma unroll 4
  for (int kq = 0; kq < 16; ++kq) {
    float w0 = ws[(kq * 4 + 0) * 64 + c];
    float w1 = ws[(kq * 4 + 1) * 64 + c];
    float w2 = ws[(kq * 4 + 2) * 64 + c];
    float w3 = ws[(kq * 4 + 3) * 64 + c];
#pragma unroll
    for (int i = 0; i < 16; ++i) {
      const float4 xv = *(const float4*)&xs[(rg + i * 4) * 64 + kq * 4];
      acc[i] += xv.x * w0 + xv.y * w1 + xv.z * w2 + xv.w * w3;
    }
  }
#pragma unroll
  for (int i = 0; i < 16; ++i)
    Y[(row0 + rg + (size_t)i * 4) * 64 + c] = acc[i];
}

// ---------- ELL gather, 2 nodes/wave, optional inline bias+relu on H rows ----------
template <int RELU>
__global__ __launch_bounds__(256) void k_gather(const float* __restrict__ H, const int* __restrict__ cnt,
                                                const int* __restrict__ col,
                                                const float* __restrict__ bias, float* __restrict__ agg) {
  int lane = threadIdx.x & 63;
  int n0 = (blockIdx.x * 4 + (threadIdx.x >> 6)) * 2;
  int n1 = n0 + 1;
  float b = RELU ? bias[lane] : 0.f;
  auto ld = [&](int s) -> float {
    float v = H[(size_t)s * 64 + lane];
    return RELU ? fmaxf(v + b, 0.f) : v;
  };
  int deg0 = cnt[n0], deg1 = cnt[n1];
  float dn0 = rsqrtf((float)deg0 + 1.0f), dn1 = rsqrtf((float)deg1 + 1.0f);
  float acc0 = ld(n0) * (dn0 * dn0);
  float acc1 = ld(n1) * (dn1 * dn1);
  int m0 = min(deg0, MAXW), m1 = min(deg1, MAXW);
  const int* c0r = col + (size_t)n0 * MAXW;
  const int* c1r = col + (size_t)n1 * MAXW;
  int myc0 = (lane < m0) ? c0r[lane] : 0;
  int myc1 = (lane < m1) ? c1r[lane] : 0;
  float md0 = (lane < m0) ? rsqrtf((float)cnt[myc0] + 1.0f) : 0.f;
  float md1 = (lane < m1) ? rsqrtf((float)cnt[myc1] + 1.0f) : 0.f;
  int mm = max(m0, m1);
  for (int j = 0; j < mm; j += 4) {
    float h[8], cc[8];
#pragma unroll
    for (int k = 0; k < 4; ++k) {
      if (j + k < m0) {          // wave-uniform branch
        int s = __shfl(myc0, j + k);
        cc[k] = __shfl(md0, j + k);
        h[k] = ld(s);
      } else { h[k] = 0.f; cc[k] = 0.f; }
      if (j + k < m1) {
        int s = __shfl(myc1, j + k);
        cc[4 + k] = __shfl(md1, j + k);
        h[4 + k] = ld(s);
      } else { h[4 + k] = 0.f; cc[4 + k] = 0.f; }
    }
#pragma unroll
    for (int k = 0; k < 4; ++k) {
      acc0 += h[k] * (cc[k] * dn0);
      acc1 += h[4 + k] * (cc[4 + k] * dn1);
    }
  }
  agg[(size_t)n0 * 64 + lane] = acc0;
  agg[(size_t)n1 * 64 + lane] = acc1;
}

// ---------- exact ELL-overflow fix-up (separate tiny kernel; RELU matches gather) ----------
template <int RELU>
__global__ __launch_bounds__(64) void k_ovf(const int2* __restrict__ ovf, const int* __restrict__ ovfcnt,
                                            const int* __restrict__ cnt, const float* __restrict__ H,
                                            const float* __restrict__ bias, float* __restrict__ agg) {
  int lane = threadIdx.x;
  float b = RELU ? bias[lane] : 0.f;
  int n = min(*ovfcnt, OVFB_CAP);
  for (int i = blockIdx.x; i < n; i += gridDim.x) {
    int d = ovf[i].x, s = ovf[i].y;
    float v = H[(size_t)s * 64 + lane];
    if (RELU) v = fmaxf(v + b, 0.f);
    v *= rsqrtf((float)cnt[s] + 1.0f) * rsqrtf((float)cnt[d] + 1.0f);
    atomicAdd(&agg[(size_t)d * 64 + lane], v);
  }
}

// ---------- node blur (pre-W2): zpre[g,t,f] = sum_rr w[rr]*G2[g,rr,t,f] ----------
__global__ __launch_bounds__(256) void k_blur(const float* __restrict__ G2, float* __restrict__ zpre) {
  int idx = blockIdx.x * 256 + threadIdx.x;
  if (idx >= NG * TT * 64) return;
  int f = idx & 63, t = (idx >> 6) & 7, g = idx >> 9;
  const float* base = G2 + ((size_t)g * 512 + (size_t)t) * 64 + f;
  float acc = 0.f;
#pragma unroll
  for (int rr = 0; rr < 64; ++rr) {
    float w = (float)(63 - rr) * (1.0f / 63.0f);
    acc += w * base[(size_t)rr * 8 * 64];
  }
  zpre[idx] = acc;
}

// ---------- classifier head: z = zpre@W2 + 32*b2, then lin1->LIF->lin2->LIF->lin3 ----------
__global__ __launch_bounds__(64) void k_head(const float* __restrict__ zpre,
    const float* __restrict__ cw, const float* __restrict__ cb,
    const float* __restrict__ l1w, const float* __restrict__ l1b,
    const float* __restrict__ l2w, const float* __restrict__ l2b,
    const float* __restrict__ l3w, const float* __restrict__ l3b,
    float* __restrict__ out) {
  __shared__ float zp[512];
  __shared__ float zs[512];
  __shared__ float r[64];
  int g = blockIdx.x, c = threadIdx.x;
#pragma unroll
  for (int i = 0; i < 8; ++i) zp[c + i * 64] = zpre[(size_t)g * 512 + c + i * 64];
  __syncthreads();
  float zt[8];
  float cbv = 32.0f * cb[c];
#pragma unroll
  for (int t = 0; t < 8; ++t) zt[t] = cbv;
  for (int k = 0; k < 64; ++k) {
    float w = cw[k * 64 + c];
#pragma unroll
    for (int t = 0; t < 8; ++t) zt[t] += zp[t * 64 + k] * w;
  }
#pragma unroll
  for (int t = 0; t < 8; ++t) zs[t * 64 + c] = zt[t];
  __syncthreads();
  float a = l1b[c];
  for (int j = 0; j < 512; ++j) a += zs[j] * l1w[j * 64 + c];
  float mem = 0.f, rate = 0.f;
#pragma unroll
  for (int s = 0; s < 4; ++s) {
    float reset = (mem > 1.0f) ? 1.0f : 0.0f;
    mem = 0.9f * mem + a - reset;
    if (mem - 1.0f > 0.0f) rate += 1.0f;
  }
  r[c] = rate * 0.25f;
  __syncthreads();
  float a2 = l2b[c];
#pragma unroll
  for (int j = 0; j < 64; ++j) a2 += r[j] * l2w[j * 64 + c];
  __syncthreads();
  mem = 0.f; rate = 0.f;
#pragma unroll
  for (int s = 0; s < 4; ++s) {
    float reset = (mem > 1.0f) ? 1.0f : 0.0f;
    mem = 0.9f * mem + a2 - reset;
    if (mem - 1.0f > 0.0f) rate += 1.0f;
  }
  r[c] = rate * 0.25f;
  __syncthreads();
  if (c < 10) {
    float o = l3b[c];
#pragma unroll
    for (int j = 0; j < 64; ++j) o += r[j] * l3w[j * 10 + c];
    out[(size_t)g * 10 + c] = o;
  }
}

extern "C" void kernel_launch(void* const* d_in, const int* in_sizes, int n_in,
                              void* d_out, int out_size, void* d_ws, size_t ws_size,
                              hipStream_t stream) {
  const float* x   = (const float*)d_in[0];
  const int*   ei  = (const int*)d_in[1];
  const float* c1w = (const float*)d_in[3];
  const float* c1b = (const float*)d_in[4];
  const float* c2w = (const float*)d_in[5];
  const float* c2b = (const float*)d_in[6];
  const float* l1w = (const float*)d_in[7];
  const float* l1b = (const float*)d_in[8];
  const float* l2w = (const float*)d_in[9];
  const float* l2b = (const float*)d_in[10];
  const float* l3w = (const float*)d_in[11];
  const float* l3b = (const float*)d_in[12];
  float* out = (float*)d_out;

  char* w = (char*)d_ws;
  size_t off = 0;
  float* bufA = (float*)(w + off); off += (size_t)NN * 64 * 4;       // 33.5 MB (pairs overlay)
  float* bufB = (float*)(w + off); off += (size_t)NN * 64 * 4;       // 33.5 MB
  int* col    = (int*)(w + off);   off += (size_t)NN * MAXW * 4;     // 16.8 MB
  int* cnt    = (int*)(w + off);   off += (size_t)NN * 4;
  unsigned char* cnt2 = (unsigned char*)(w + off); off += (size_t)NBLK * NB; // 0.5 MB
  float* zpre = (float*)(w + off); off += (size_t)NG * TT * 64 * 4;  // 0.5 MB
  int* meta   = (int*)(w + off);   off += 16 * 4;
  int2* ovfA  = (int2*)(w + off);  off += (size_t)OVFA_CAP * 8;
  int2* ovfB  = (int2*)(w + off);  off += (size_t)OVFB_CAP * 8;
  int* ovfAcnt = meta;
  int* ovfBcnt = meta + 1;
  int* pairs   = (int*)bufA;       // 1024*512*16*4 = 33.5 MB, dead before GEMM1

  // graph build
  k_zero_i<<<1, 256, 0, stream>>>(meta, 16);
  k_part2<<<NBLK, 256, 0, stream>>>(ei, pairs, cnt2, ovfAcnt, ovfA);
  k_bucket<<<NB, 256, 0, stream>>>(pairs, cnt2, col, cnt, ovfAcnt, ovfA, ovfBcnt, ovfB);

  // layer 1: H1 = x @ W1 (bufA); agg1 = S*H1 (bufB)
  k_gemm<<<NN / 64, 256, 0, stream>>>(x, c1w, bufA);
  k_gather<0><<<NN / 8, 256, 0, stream>>>(bufA, cnt, col, nullptr, bufB);
  k_ovf<0><<<32, 64, 0, stream>>>(ovfB, ovfBcnt, cnt, bufA, nullptr, bufB);

  // layer 2 (W2 deferred past blur): G2 = S*relu(agg1 + b1) (bufA)
  k_gather<1><<<NN / 8, 256, 0, stream>>>(bufB, cnt, col, c1b, bufA);
  k_ovf<1><<<32, 64, 0, stream>>>(ovfB, ovfBcnt, cnt, bufB, c1b, bufA);

  // blur (pre-W2) + head (applies W2 + 32*b2, then MLP/LIF)
  k_blur<<<NG * TT * 64 / 256, 256, 0, stream>>>(bufA, zpre);
  k_head<<<NG, 64, 0, stream>>>(zpre, c2w, c2b, l1w, l1b, l2w, l2b, l3w, l3b, out);
}

// Round 11
// 312.560 us; speedup vs baseline: 1.3046x; 1.1242x over previous
//
#include <hip/hip_runtime.h>
#include <hip/hip_bf16.h>

#define NN 131072      // nodes
#define EE 2097152     // edges
#define NG 256         // graphs
#define TT 8
#define NB 512         // dst buckets (256 nodes each)
#define NBLK 1024      // partition blocks (2048 edges each)
#define SCAP 16        // per-(block,bucket) segment capacity
#define MAXW 32        // ELL width (overflow -> exact k_ovf fix-up)
#define OVFA_CAP 4096
#define OVFB_CAP 16384

// ---------- zero (int) ----------
__global__ __launch_bounds__(256) void k_zero_i(int* __restrict__ p, int n) {
  int i = blockIdx.x * 256 + threadIdx.x;
  if (i < n) p[i] = 0;
}

// ---------- pass 1: block-private partition, LDS cursors, block-major layout ----------
__global__ __launch_bounds__(256) void k_part2(const int* __restrict__ ei, int* __restrict__ pairs,
                                               unsigned char* __restrict__ cnt2, int* __restrict__ ovfAcnt,
                                               int2* __restrict__ ovfA) {
  __shared__ int lcur[NB];
  int tid = threadIdx.x, blk = blockIdx.x;
  lcur[tid] = 0; lcur[tid + 256] = 0;
  __syncthreads();
  int e0 = blk * (EE / NBLK);
#pragma unroll
  for (int i = 0; i < (EE / NBLK) / 256; ++i) {
    int e = e0 + i * 256 + tid;
    int s = ei[e], d = ei[EE + e];
    int b = d >> 8;
    int k = atomicAdd(&lcur[b], 1);
    if (k < SCAP)
      pairs[((size_t)blk * NB + b) * SCAP + k] = ((d & 255) << 17) | s;
    else {
      int oi = atomicAdd(ovfAcnt, 1);
      if (oi < OVFA_CAP) ovfA[oi] = make_int2(d, s);
    }
  }
  __syncthreads();
  cnt2[(size_t)blk * NB + tid] = (unsigned char)min(lcur[tid], SCAP);
  cnt2[(size_t)blk * NB + tid + 256] = (unsigned char)min(lcur[tid + 256], SCAP);
}

// ---------- pass 2: per-bucket ELL build in LDS ----------
__global__ __launch_bounds__(256) void k_bucket(const int* __restrict__ pairs, const unsigned char* __restrict__ cnt2,
                                                int* __restrict__ col, int* __restrict__ cnt,
                                                const int* __restrict__ ovfAcnt, const int2* __restrict__ ovfA,
                                                int* __restrict__ ovfBcnt, int2* __restrict__ ovfB) {
  __shared__ int lcnt[256];
  __shared__ int lell[256 * MAXW];
  __shared__ unsigned char scnt[NBLK];
  int b = blockIdx.x, tid = threadIdx.x;
  lcnt[tid] = 0;
#pragma unroll
  for (int i = 0; i < NBLK / 256; ++i)
    scnt[tid + i * 256] = cnt2[(size_t)(tid + i * 256) * NB + b];
  __syncthreads();
  for (int idx = tid; idx < NBLK * SCAP; idx += 256) {
    int blk = idx >> 4, slot = idx & (SCAP - 1);
    if (slot < (int)scnt[blk]) {
      int p = pairs[(size_t)blk * (NB * SCAP) + b * SCAP + slot];
      int s = p & 0x1FFFF, dl = p >> 17;
      int k = atomicAdd(&lcnt[dl], 1);
      if (k < MAXW) lell[dl * MAXW + k] = s;
      else {
        int oi = atomicAdd(ovfBcnt, 1);
        if (oi < OVFB_CAP) ovfB[oi] = make_int2(b * 256 + dl, s);
      }
    }
  }
  int na = min(*ovfAcnt, OVFA_CAP);
  for (int i = tid; i < na; i += 256) {
    int d = ovfA[i].x, s = ovfA[i].y;
    if ((d >> 8) == b) {
      int dl = d & 255;
      int k = atomicAdd(&lcnt[dl], 1);
      if (k < MAXW) lell[dl * MAXW + k] = s;
      else {
        int oi = atomicAdd(ovfBcnt, 1);
        if (oi < OVFB_CAP) ovfB[oi] = make_int2(d, s);
      }
    }
  }
  __syncthreads();
  int4* dst4 = (int4*)(col + (size_t)b * 256 * MAXW);
  const int4* src4 = (const int4*)lell;
#pragma unroll
  for (int i = 0; i < (256 * MAXW / 4) / 256; ++i)
    dst4[tid + i * 256] = src4[tid + i * 256];
  cnt[b * 256 + tid] = lcnt[tid];
}

// ---------- GEMM (layer 1): Y = X @ W ----------
__global__ __launch_bounds__(256) void k_gemm(const float* __restrict__ X, const float* __restrict__ W,
                                              float* __restrict__ Y) {
  __shared__ float xs[64 * 64];
  __shared__ float ws[64 * 64];
  int tid = threadIdx.x;
  size_t row0 = (size_t)blockIdx.x * 64;
#pragma unroll
  for (int i = 0; i < 16; ++i) ws[tid + i * 256] = W[tid + i * 256];
#pragma unroll
  for (int i = 0; i < 4; ++i) {
    int idx = tid + i * 256;
    int r = idx >> 4, q = idx & 15;
    float4 v = ((const float4*)(X + (row0 + r) * 64))[q];
    *(float4*)&xs[idx * 4] = v;
  }
  __syncthreads();
  int c = tid & 63, rg = tid >> 6;
  float acc[16];
#pragma unroll
  for (int i = 0; i < 16; ++i) acc[i] = 0.f;
#pragma unroll 4
  for (int kq = 0; kq < 16; ++kq) {
    float w0 = ws[(kq * 4 + 0) * 64 + c];
    float w1 = ws[(kq * 4 + 1) * 64 + c];
    float w2 = ws[(kq * 4 + 2) * 64 + c];
    float w3 = ws[(kq * 4 + 3) * 64 + c];
#pragma unroll
    for (int i = 0; i < 16; ++i) {
      const float4 xv = *(const float4*)&xs[(rg + i * 4) * 64 + kq * 4];
      acc[i] += xv.x * w0 + xv.y * w1 + xv.z * w2 + xv.w * w3;
    }
  }
#pragma unroll
  for (int i = 0; i < 16; ++i)
    Y[(row0 + rg + (size_t)i * 4) * 64 + c] = acc[i];
}

// ---------- ELL gather, 2 nodes per wave (ILP): lane = feature  [exact R8 source] ----------
__global__ __launch_bounds__(256) void k_gather_ell(const float* __restrict__ H, const int* __restrict__ cnt,
                                                    const int* __restrict__ col, float* __restrict__ agg) {
  int lane = threadIdx.x & 63;
  int n0 = (blockIdx.x * 4 + (threadIdx.x >> 6)) * 2;
  int n1 = n0 + 1;
  int deg0 = cnt[n0], deg1 = cnt[n1];
  float dn0 = rsqrtf((float)deg0 + 1.0f), dn1 = rsqrtf((float)deg1 + 1.0f);
  float acc0 = H[(size_t)n0 * 64 + lane] * (dn0 * dn0);
  float acc1 = H[(size_t)n1 * 64 + lane] * (dn1 * dn1);
  int m0 = min(deg0, MAXW), m1 = min(deg1, MAXW);
  const int* c0r = col + (size_t)n0 * MAXW;
  const int* c1r = col + (size_t)n1 * MAXW;
  int myc0 = (lane < m0) ? c0r[lane] : 0;
  int myc1 = (lane < m1) ? c1r[lane] : 0;
  float md0 = (lane < m0) ? rsqrtf((float)cnt[myc0] + 1.0f) : 0.f;
  float md1 = (lane < m1) ? rsqrtf((float)cnt[myc1] + 1.0f) : 0.f;
  int mm = max(m0, m1);
  for (int j = 0; j < mm; j += 4) {
    float h[8], cc[8];
#pragma unroll
    for (int k = 0; k < 4; ++k) {
      if (j + k < m0) {          // wave-uniform branch
        int s = __shfl(myc0, j + k);
        cc[k] = __shfl(md0, j + k);
        h[k] = H[(size_t)s * 64 + lane];
      } else { h[k] = 0.f; cc[k] = 0.f; }
      if (j + k < m1) {
        int s = __shfl(myc1, j + k);
        cc[4 + k] = __shfl(md1, j + k);
        h[4 + k] = H[(size_t)s * 64 + lane];
      } else { h[4 + k] = 0.f; cc[4 + k] = 0.f; }
    }
#pragma unroll
    for (int k = 0; k < 4; ++k) {
      acc0 += h[k] * (cc[k] * dn0);
      acc1 += h[4 + k] * (cc[4 + k] * dn1);
    }
  }
  agg[(size_t)n0 * 64 + lane] = acc0;
  agg[(size_t)n1 * 64 + lane] = acc1;
}

// ---------- exact ELL-overflow fix-up (raw contributions)  [exact R8 source] ----------
__global__ __launch_bounds__(64) void k_ovf(const int2* __restrict__ ovf, const int* __restrict__ ovfcnt,
                                            const int* __restrict__ cnt, const float* __restrict__ H,
                                            float* __restrict__ agg) {
  int lane = threadIdx.x;
  int n = min(*ovfcnt, OVFB_CAP);
  for (int i = blockIdx.x; i < n; i += gridDim.x) {
    int d = ovf[i].x, s = ovf[i].y;
    float v = H[(size_t)s * 64 + lane] * rsqrtf((float)cnt[s] + 1.0f) * rsqrtf((float)cnt[d] + 1.0f);
    atomicAdd(&agg[(size_t)d * 64 + lane], v);
  }
}

// ---------- in-place relu(x + b) over [NN][64], float4-vectorized ----------
__global__ __launch_bounds__(256) void k_relub(float* __restrict__ a, const float* __restrict__ b) {
  int i = blockIdx.x * 256 + threadIdx.x;   // float4 index, total NN*16
  float4 bb = ((const float4*)b)[i & 15];
  float4 v = ((float4*)a)[i];
  v.x = fmaxf(v.x + bb.x, 0.f);
  v.y = fmaxf(v.y + bb.y, 0.f);
  v.z = fmaxf(v.z + bb.z, 0.f);
  v.w = fmaxf(v.w + bb.w, 0.f);
  ((float4*)a)[i] = v;
}

// ---------- node blur (pre-W2): zpre[g,t,f] = sum_rr w[rr]*G2[g,rr,t,f] ----------
__global__ __launch_bounds__(256) void k_blur(const float* __restrict__ G2, float* __restrict__ zpre) {
  int idx = blockIdx.x * 256 + threadIdx.x;
  if (idx >= NG * TT * 64) return;
  int f = idx & 63, t = (idx >> 6) & 7, g = idx >> 9;
  const float* base = G2 + ((size_t)g * 512 + (size_t)t) * 64 + f;
  float acc = 0.f;
#pragma unroll
  for (int rr = 0; rr < 64; ++rr) {
    float w = (float)(63 - rr) * (1.0f / 63.0f);
    acc += w * base[(size_t)rr * 8 * 64];
  }
  zpre[idx] = acc;
}

// ---------- classifier head: z = zpre@W2 + 32*b2, then lin1->LIF->lin2->LIF->lin3 ----------
__global__ __launch_bounds__(64) void k_head(const float* __restrict__ zpre,
    const float* __restrict__ cw, const float* __restrict__ cb,
    const float* __restrict__ l1w, const float* __restrict__ l1b,
    const float* __restrict__ l2w, const float* __restrict__ l2b,
    const float* __restrict__ l3w, const float* __restrict__ l3b,
    float* __restrict__ out) {
  __shared__ float zp[512];
  __shared__ float zs[512];
  __shared__ float r[64];
  int g = blockIdx.x, c = threadIdx.x;
#pragma unroll
  for (int i = 0; i < 8; ++i) zp[c + i * 64] = zpre[(size_t)g * 512 + c + i * 64];
  __syncthreads();
  float zt[8];
  float cbv = 32.0f * cb[c];
#pragma unroll
  for (int t = 0; t < 8; ++t) zt[t] = cbv;
  for (int k = 0; k < 64; ++k) {
    float w = cw[k * 64 + c];
#pragma unroll
    for (int t = 0; t < 8; ++t) zt[t] += zp[t * 64 + k] * w;
  }
#pragma unroll
  for (int t = 0; t < 8; ++t) zs[t * 64 + c] = zt[t];
  __syncthreads();
  float a = l1b[c];
  for (int j = 0; j < 512; ++j) a += zs[j] * l1w[j * 64 + c];
  float mem = 0.f, rate = 0.f;
#pragma unroll
  for (int s = 0; s < 4; ++s) {
    float reset = (mem > 1.0f) ? 1.0f : 0.0f;
    mem = 0.9f * mem + a - reset;
    if (mem - 1.0f > 0.0f) rate += 1.0f;
  }
  r[c] = rate * 0.25f;
  __syncthreads();
  float a2 = l2b[c];
#pragma unroll
  for (int j = 0; j < 64; ++j) a2 += r[j] * l2w[j * 64 + c];
  __syncthreads();
  mem = 0.f; rate = 0.f;
#pragma unroll
  for (int s = 0; s < 4; ++s) {
    float reset = (mem > 1.0f) ? 1.0f : 0.0f;
    mem = 0.9f * mem + a2 - reset;
    if (mem - 1.0f > 0.0f) rate += 1.0f;
  }
  r[c] = rate * 0.25f;
  __syncthreads();
  if (c < 10) {
    float o = l3b[c];
#pragma unroll
    for (int j = 0; j < 64; ++j) o += r[j] * l3w[j * 10 + c];
    out[(size_t)g * 10 + c] = o;
  }
}

extern "C" void kernel_launch(void* const* d_in, const int* in_sizes, int n_in,
                              void* d_out, int out_size, void* d_ws, size_t ws_size,
                              hipStream_t stream) {
  const float* x   = (const float*)d_in[0];
  const int*   ei  = (const int*)d_in[1];
  const float* c1w = (const float*)d_in[3];
  const float* c1b = (const float*)d_in[4];
  const float* c2w = (const float*)d_in[5];
  const float* c2b = (const float*)d_in[6];
  const float* l1w = (const float*)d_in[7];
  const float* l1b = (const float*)d_in[8];
  const float* l2w = (const float*)d_in[9];
  const float* l2b = (const float*)d_in[10];
  const float* l3w = (const float*)d_in[11];
  const float* l3b = (const float*)d_in[12];
  float* out = (float*)d_out;

  char* w = (char*)d_ws;
  size_t off = 0;
  float* bufA = (float*)(w + off); off += (size_t)NN * 64 * 4;       // 33.5 MB (pairs overlay)
  float* bufB = (float*)(w + off); off += (size_t)NN * 64 * 4;       // 33.5 MB
  int* col    = (int*)(w + off);   off += (size_t)NN * MAXW * 4;     // 16.8 MB
  int* cnt    = (int*)(w + off);   off += (size_t)NN * 4;
  unsigned char* cnt2 = (unsigned char*)(w + off); off += (size_t)NBLK * NB; // 0.5 MB
  float* zpre = (float*)(w + off); off += (size_t)NG * TT * 64 * 4;  // 0.5 MB
  int* meta   = (int*)(w + off);   off += 16 * 4;
  int2* ovfA  = (int2*)(w + off);  off += (size_t)OVFA_CAP * 8;
  int2* ovfB  = (int2*)(w + off);  off += (size_t)OVFB_CAP * 8;
  int* ovfAcnt = meta;
  int* ovfBcnt = meta + 1;
  int* pairs   = (int*)bufA;       // 1024*512*16*4 = 33.5 MB, dead before GEMM1

  // graph build
  k_zero_i<<<1, 256, 0, stream>>>(meta, 16);
  k_part2<<<NBLK, 256, 0, stream>>>(ei, pairs, cnt2, ovfAcnt, ovfA);
  k_bucket<<<NB, 256, 0, stream>>>(pairs, cnt2, col, cnt, ovfAcnt, ovfA, ovfBcnt, ovfB);

  // layer 1: H1 = x @ W1 (bufA); agg1 = S*H1 (bufB, raw)
  k_gemm<<<NN / 64, 256, 0, stream>>>(x, c1w, bufA);
  k_gather_ell<<<NN / 8, 256, 0, stream>>>(bufA, cnt, col, bufB);
  k_ovf<<<32, 64, 0, stream>>>(ovfB, ovfBcnt, cnt, bufA, bufB);
  // R = relu(agg1 + b1) in place
  k_relub<<<NN * 16 / 256, 256, 0, stream>>>(bufB, c1b);

  // layer 2 (W2 deferred past blur): G2 = S*R (bufA)
  k_gather_ell<<<NN / 8, 256, 0, stream>>>(bufB, cnt, col, bufA);
  k_ovf<<<32, 64, 0, stream>>>(ovfB, ovfBcnt, cnt, bufB, bufA);

  // blur (pre-W2) + head (applies W2 + 32*b2, then MLP/LIF)
  k_blur<<<NG * TT * 64 / 256, 256, 0, stream>>>(bufA, zpre);
  k_head<<<NG, 64, 0, stream>>>(zpre, c2w, c2b, l1w, l1b, l2w, l2b, l3w, l3b, out);
}

// Round 12
// 291.850 us; speedup vs baseline: 1.3972x; 1.0710x over previous
//
#include <hip/hip_runtime.h>
#include <hip/hip_bf16.h>

#define NN 131072      // nodes
#define EE 2097152     // edges
#define NG 256         // graphs
#define TT 8
#define NB 512         // dst buckets (256 nodes each)
#define NBLK 1024      // partition blocks (2048 edges each)
#define SCAP 16        // per-(block,bucket) segment capacity
#define MAXW 32        // ELL width (overflow -> exact k_ovf fix-up)
#define OVFA_CAP 4096
#define OVFB_CAP 16384

// ---------- zero (int) ----------
__global__ __launch_bounds__(256) void k_zero_i(int* __restrict__ p, int n) {
  int i = blockIdx.x * 256 + threadIdx.x;
  if (i < n) p[i] = 0;
}

// ---------- pass 1: block-private partition, LDS staging, dense coalesced writeout ----------
__global__ __launch_bounds__(256) void k_part2(const int* __restrict__ ei, int* __restrict__ pairs,
                                               unsigned char* __restrict__ cnt2, int* __restrict__ ovfAcnt,
                                               int2* __restrict__ ovfA) {
  __shared__ int lcur[NB];
  __shared__ int stage[NB * SCAP];   // 32 KB
  int tid = threadIdx.x, blk = blockIdx.x;
  lcur[tid] = 0; lcur[tid + 256] = 0;
  __syncthreads();
  int e0 = blk * (EE / NBLK);
#pragma unroll
  for (int i = 0; i < (EE / NBLK) / 256; ++i) {
    int e = e0 + i * 256 + tid;
    int s = ei[e], d = ei[EE + e];
    int b = d >> 8;
    int k = atomicAdd(&lcur[b], 1);
    if (k < SCAP)
      stage[b * SCAP + k] = ((d & 255) << 17) | s;
    else {
      int oi = atomicAdd(ovfAcnt, 1);
      if (oi < OVFA_CAP) ovfA[oi] = make_int2(d, s);
    }
  }
  __syncthreads();
  // dense int4 writeout of the whole staged region (garbage slots never read: bucket checks scnt)
  int4* dst4 = (int4*)(pairs + (size_t)blk * NB * SCAP);
  const int4* src4 = (const int4*)stage;
#pragma unroll
  for (int i = 0; i < (NB * SCAP / 4) / 256; ++i)
    dst4[tid + i * 256] = src4[tid + i * 256];
  cnt2[(size_t)blk * NB + tid] = (unsigned char)min(lcur[tid], SCAP);
  cnt2[(size_t)blk * NB + tid + 256] = (unsigned char)min(lcur[tid + 256], SCAP);
}

// ---------- pass 2: per-bucket ELL build in LDS ----------
__global__ __launch_bounds__(256) void k_bucket(const int* __restrict__ pairs, const unsigned char* __restrict__ cnt2,
                                                int* __restrict__ col, int* __restrict__ cnt,
                                                const int* __restrict__ ovfAcnt, const int2* __restrict__ ovfA,
                                                int* __restrict__ ovfBcnt, int2* __restrict__ ovfB) {
  __shared__ int lcnt[256];
  __shared__ int lell[256 * MAXW];
  __shared__ unsigned char scnt[NBLK];
  int b = blockIdx.x, tid = threadIdx.x;
  lcnt[tid] = 0;
#pragma unroll
  for (int i = 0; i < NBLK / 256; ++i)
    scnt[tid + i * 256] = cnt2[(size_t)(tid + i * 256) * NB + b];
  __syncthreads();
  for (int idx = tid; idx < NBLK * SCAP; idx += 256) {
    int blk = idx >> 4, slot = idx & (SCAP - 1);
    if (slot < (int)scnt[blk]) {
      int p = pairs[(size_t)blk * (NB * SCAP) + b * SCAP + slot];
      int s = p & 0x1FFFF, dl = p >> 17;
      int k = atomicAdd(&lcnt[dl], 1);
      if (k < MAXW) lell[dl * MAXW + k] = s;
      else {
        int oi = atomicAdd(ovfBcnt, 1);
        if (oi < OVFB_CAP) ovfB[oi] = make_int2(b * 256 + dl, s);
      }
    }
  }
  int na = min(*ovfAcnt, OVFA_CAP);
  for (int i = tid; i < na; i += 256) {
    int d = ovfA[i].x, s = ovfA[i].y;
    if ((d >> 8) == b) {
      int dl = d & 255;
      int k = atomicAdd(&lcnt[dl], 1);
      if (k < MAXW) lell[dl * MAXW + k] = s;
      else {
        int oi = atomicAdd(ovfBcnt, 1);
        if (oi < OVFB_CAP) ovfB[oi] = make_int2(d, s);
      }
    }
  }
  __syncthreads();
  int4* dst4 = (int4*)(col + (size_t)b * 256 * MAXW);
  const int4* src4 = (const int4*)lell;
#pragma unroll
  for (int i = 0; i < (256 * MAXW / 4) / 256; ++i)
    dst4[tid + i * 256] = src4[tid + i * 256];
  cnt[b * 256 + tid] = lcnt[tid];
}

// ---------- GEMM (layer 1): Y = X @ W ----------
__global__ __launch_bounds__(256) void k_gemm(const float* __restrict__ X, const float* __restrict__ W,
                                              float* __restrict__ Y) {
  __shared__ float xs[64 * 64];
  __shared__ float ws[64 * 64];
  int tid = threadIdx.x;
  size_t row0 = (size_t)blockIdx.x * 64;
#pragma unroll
  for (int i = 0; i < 16; ++i) ws[tid + i * 256] = W[tid + i * 256];
#pragma unroll
  for (int i = 0; i < 4; ++i) {
    int idx = tid + i * 256;
    int r = idx >> 4, q = idx & 15;
    float4 v = ((const float4*)(X + (row0 + r) * 64))[q];
    *(float4*)&xs[idx * 4] = v;
  }
  __syncthreads();
  int c = tid & 63, rg = tid >> 6;
  float acc[16];
#pragma unroll
  for (int i = 0; i < 16; ++i) acc[i] = 0.f;
#pragma unroll 4
  for (int kq = 0; kq < 16; ++kq) {
    float w0 = ws[(kq * 4 + 0) * 64 + c];
    float w1 = ws[(kq * 4 + 1) * 64 + c];
    float w2 = ws[(kq * 4 + 2) * 64 + c];
    float w3 = ws[(kq * 4 + 3) * 64 + c];
#pragma unroll
    for (int i = 0; i < 16; ++i) {
      const float4 xv = *(const float4*)&xs[(rg + i * 4) * 64 + kq * 4];
      acc[i] += xv.x * w0 + xv.y * w1 + xv.z * w2 + xv.w * w3;
    }
  }
#pragma unroll
  for (int i = 0; i < 16; ++i)
    Y[(row0 + rg + (size_t)i * 4) * 64 + c] = acc[i];
}

// ---------- ELL gather, 2 nodes per wave (ILP): lane = feature  [FROZEN SOURCE - do not refactor] ----------
__global__ __launch_bounds__(256) void k_gather_ell(const float* __restrict__ H, const int* __restrict__ cnt,
                                                    const int* __restrict__ col, float* __restrict__ agg) {
  int lane = threadIdx.x & 63;
  int n0 = (blockIdx.x * 4 + (threadIdx.x >> 6)) * 2;
  int n1 = n0 + 1;
  int deg0 = cnt[n0], deg1 = cnt[n1];
  float dn0 = rsqrtf((float)deg0 + 1.0f), dn1 = rsqrtf((float)deg1 + 1.0f);
  float acc0 = H[(size_t)n0 * 64 + lane] * (dn0 * dn0);
  float acc1 = H[(size_t)n1 * 64 + lane] * (dn1 * dn1);
  int m0 = min(deg0, MAXW), m1 = min(deg1, MAXW);
  const int* c0r = col + (size_t)n0 * MAXW;
  const int* c1r = col + (size_t)n1 * MAXW;
  int myc0 = (lane < m0) ? c0r[lane] : 0;
  int myc1 = (lane < m1) ? c1r[lane] : 0;
  float md0 = (lane < m0) ? rsqrtf((float)cnt[myc0] + 1.0f) : 0.f;
  float md1 = (lane < m1) ? rsqrtf((float)cnt[myc1] + 1.0f) : 0.f;
  int mm = max(m0, m1);
  for (int j = 0; j < mm; j += 4) {
    float h[8], cc[8];
#pragma unroll
    for (int k = 0; k < 4; ++k) {
      if (j + k < m0) {          // wave-uniform branch
        int s = __shfl(myc0, j + k);
        cc[k] = __shfl(md0, j + k);
        h[k] = H[(size_t)s * 64 + lane];
      } else { h[k] = 0.f; cc[k] = 0.f; }
      if (j + k < m1) {
        int s = __shfl(myc1, j + k);
        cc[4 + k] = __shfl(md1, j + k);
        h[4 + k] = H[(size_t)s * 64 + lane];
      } else { h[4 + k] = 0.f; cc[4 + k] = 0.f; }
    }
#pragma unroll
    for (int k = 0; k < 4; ++k) {
      acc0 += h[k] * (cc[k] * dn0);
      acc1 += h[4 + k] * (cc[4 + k] * dn1);
    }
  }
  agg[(size_t)n0 * 64 + lane] = acc0;
  agg[(size_t)n1 * 64 + lane] = acc1;
}

// ---------- exact ELL-overflow fix-up (raw contributions) ----------
__global__ __launch_bounds__(64) void k_ovf(const int2* __restrict__ ovf, const int* __restrict__ ovfcnt,
                                            const int* __restrict__ cnt, const float* __restrict__ H,
                                            float* __restrict__ agg) {
  int lane = threadIdx.x;
  int n = min(*ovfcnt, OVFB_CAP);
  for (int i = blockIdx.x; i < n; i += gridDim.x) {
    int d = ovf[i].x, s = ovf[i].y;
    float v = H[(size_t)s * 64 + lane] * rsqrtf((float)cnt[s] + 1.0f) * rsqrtf((float)cnt[d] + 1.0f);
    atomicAdd(&agg[(size_t)d * 64 + lane], v);
  }
}

// ---------- in-place relu(x + b) over [NN][64], float4-vectorized ----------
__global__ __launch_bounds__(256) void k_relub(float* __restrict__ a, const float* __restrict__ b) {
  int i = blockIdx.x * 256 + threadIdx.x;   // float4 index, total NN*16
  float4 bb = ((const float4*)b)[i & 15];
  float4 v = ((float4*)a)[i];
  v.x = fmaxf(v.x + bb.x, 0.f);
  v.y = fmaxf(v.y + bb.y, 0.f);
  v.z = fmaxf(v.z + bb.z, 0.f);
  v.w = fmaxf(v.w + bb.w, 0.f);
  ((float4*)a)[i] = v;
}

// ---------- node blur (pre-W2): zpre[g,t,f] = sum_rr w[rr]*G2[g,rr,t,f] ----------
__global__ __launch_bounds__(256) void k_blur(const float* __restrict__ G2, float* __restrict__ zpre) {
  int idx = blockIdx.x * 256 + threadIdx.x;
  if (idx >= NG * TT * 64) return;
  int f = idx & 63, t = (idx >> 6) & 7, g = idx >> 9;
  const float* base = G2 + ((size_t)g * 512 + (size_t)t) * 64 + f;
  float acc = 0.f;
#pragma unroll
  for (int rr = 0; rr < 64; ++rr) {
    float w = (float)(63 - rr) * (1.0f / 63.0f);
    acc += w * base[(size_t)rr * 8 * 64];
  }
  zpre[idx] = acc;
}

// ---------- classifier head: z = zpre@W2 + 32*b2, then lin1->LIF->lin2->LIF->lin3 ----------
__global__ __launch_bounds__(64) void k_head(const float* __restrict__ zpre,
    const float* __restrict__ cw, const float* __restrict__ cb,
    const float* __restrict__ l1w, const float* __restrict__ l1b,
    const float* __restrict__ l2w, const float* __restrict__ l2b,
    const float* __restrict__ l3w, const float* __restrict__ l3b,
    float* __restrict__ out) {
  __shared__ float zp[512];
  __shared__ float zs[512];
  __shared__ float r[64];
  int g = blockIdx.x, c = threadIdx.x;
#pragma unroll
  for (int i = 0; i < 8; ++i) zp[c + i * 64] = zpre[(size_t)g * 512 + c + i * 64];
  __syncthreads();
  float zt[8];
  float cbv = 32.0f * cb[c];
#pragma unroll
  for (int t = 0; t < 8; ++t) zt[t] = cbv;
  for (int k = 0; k < 64; ++k) {
    float w = cw[k * 64 + c];
#pragma unroll
    for (int t = 0; t < 8; ++t) zt[t] += zp[t * 64 + k] * w;
  }
#pragma unroll
  for (int t = 0; t < 8; ++t) zs[t * 64 + c] = zt[t];
  __syncthreads();
  float a = l1b[c];
  for (int j = 0; j < 512; ++j) a += zs[j] * l1w[j * 64 + c];
  float mem = 0.f, rate = 0.f;
#pragma unroll
  for (int s = 0; s < 4; ++s) {
    float reset = (mem > 1.0f) ? 1.0f : 0.0f;
    mem = 0.9f * mem + a - reset;
    if (mem - 1.0f > 0.0f) rate += 1.0f;
  }
  r[c] = rate * 0.25f;
  __syncthreads();
  float a2 = l2b[c];
#pragma unroll
  for (int j = 0; j < 64; ++j) a2 += r[j] * l2w[j * 64 + c];
  __syncthreads();
  mem = 0.f; rate = 0.f;
#pragma unroll
  for (int s = 0; s < 4; ++s) {
    float reset = (mem > 1.0f) ? 1.0f : 0.0f;
    mem = 0.9f * mem + a2 - reset;
    if (mem - 1.0f > 0.0f) rate += 1.0f;
  }
  r[c] = rate * 0.25f;
  __syncthreads();
  if (c < 10) {
    float o = l3b[c];
#pragma unroll
    for (int j = 0; j < 64; ++j) o += r[j] * l3w[j * 10 + c];
    out[(size_t)g * 10 + c] = o;
  }
}

extern "C" void kernel_launch(void* const* d_in, const int* in_sizes, int n_in,
                              void* d_out, int out_size, void* d_ws, size_t ws_size,
                              hipStream_t stream) {
  const float* x   = (const float*)d_in[0];
  const int*   ei  = (const int*)d_in[1];
  const float* c1w = (const float*)d_in[3];
  const float* c1b = (const float*)d_in[4];
  const float* c2w = (const float*)d_in[5];
  const float* c2b = (const float*)d_in[6];
  const float* l1w = (const float*)d_in[7];
  const float* l1b = (const float*)d_in[8];
  const float* l2w = (const float*)d_in[9];
  const float* l2b = (const float*)d_in[10];
  const float* l3w = (const float*)d_in[11];
  const float* l3b = (const float*)d_in[12];
  float* out = (float*)d_out;

  char* w = (char*)d_ws;
  size_t off = 0;
  float* bufA = (float*)(w + off); off += (size_t)NN * 64 * 4;       // 33.5 MB (pairs overlay)
  float* bufB = (float*)(w + off); off += (size_t)NN * 64 * 4;       // 33.5 MB
  int* col    = (int*)(w + off);   off += (size_t)NN * MAXW * 4;     // 16.8 MB
  int* cnt    = (int*)(w + off);   off += (size_t)NN * 4;
  unsigned char* cnt2 = (unsigned char*)(w + off); off += (size_t)NBLK * NB; // 0.5 MB
  float* zpre = (float*)(w + off); off += (size_t)NG * TT * 64 * 4;  // 0.5 MB
  int* meta   = (int*)(w + off);   off += 16 * 4;
  int2* ovfA  = (int2*)(w + off);  off += (size_t)OVFA_CAP * 8;
  int2* ovfB  = (int2*)(w + off);  off += (size_t)OVFB_CAP * 8;
  int* ovfAcnt = meta;
  int* ovfBcnt = meta + 1;
  int* pairs   = (int*)bufA;       // 1024*512*16*4 = 33.5 MB, dead before GEMM1

  // graph build
  k_zero_i<<<1, 256, 0, stream>>>(meta, 16);
  k_part2<<<NBLK, 256, 0, stream>>>(ei, pairs, cnt2, ovfAcnt, ovfA);
  k_bucket<<<NB, 256, 0, stream>>>(pairs, cnt2, col, cnt, ovfAcnt, ovfA, ovfBcnt, ovfB);

  // layer 1: H1 = x @ W1 (bufA); agg1 = S*H1 (bufB, raw)
  k_gemm<<<NN / 64, 256, 0, stream>>>(x, c1w, bufA);
  k_gather_ell<<<NN / 8, 256, 0, stream>>>(bufA, cnt, col, bufB);
  k_ovf<<<32, 64, 0, stream>>>(ovfB, ovfBcnt, cnt, bufA, bufB);
  // R = relu(agg1 + b1) in place
  k_relub<<<NN * 16 / 256, 256, 0, stream>>>(bufB, c1b);

  // layer 2 (W2 deferred past blur): G2 = S*R (bufA)
  k_gather_ell<<<NN / 8, 256, 0, stream>>>(bufB, cnt, col, bufA);
  k_ovf<<<32, 64, 0, stream>>>(ovfB, ovfBcnt, cnt, bufB, bufA);

  // blur (pre-W2) + head (applies W2 + 32*b2, then MLP/LIF)
  k_blur<<<NG * TT * 64 / 256, 256, 0, stream>>>(bufA, zpre);
  k_head<<<NG, 64, 0, stream>>>(zpre, c2w, c2b, l1w, l1b, l2w, l2b, l3w, l3b, out);
}